// Round 2
// baseline (1165.712 us; speedup 1.0000x reference)
//
#include <hip/hip_runtime.h>

// FiberConv: out[b, t*OUT+o] = sum_{s,i} kernel[t,s,o,i] * x[b, s*IN+i] + bias[o]
// GEMM: X[400000 x 384] * B^T, B[n=t*32+o][k=s*32+i]. f32 I/O, bf16 MFMA inside.
// v3: drop LDS staging (B is 288 KB, L2-resident; fragment-ordered direct reads
//     are perfectly coalesced) -> no barriers, waves run free; occupancy 2->3
//     waves/SIMD; nontemporal X loads + out stores to keep B hot in L1/L2.

using f32x4  = __attribute__((ext_vector_type(4))) float;
using bf16x8 = __attribute__((ext_vector_type(8))) __bf16;
using short8 = __attribute__((ext_vector_type(8))) short;

constexpr int T_   = 12;
constexpr int S_   = 12;
constexpr int ATTR = 3;
constexpr int IN   = 32;
constexpr int OUT  = 32;
constexpr int K    = S_ * IN;    // 384
constexpr int N    = T_ * OUT;   // 384
constexpr int NB   = 400000;     // batch rows (3125 * 128 exact)
constexpr int KB_CNT = K / 32;   // 12 MFMA K-steps
constexpr int CT_CNT = N / 16;   // 24 channel tiles of 16
constexpr int FRAG_SHORTS = 64 * 8;               // 512 shorts = 1024 B per (ct,kb) fragment
constexpr int CT_SHORTS   = KB_CNT * FRAG_SHORTS; // 6144 shorts = 12 KB per ct

__device__ __forceinline__ unsigned short f2bf(float f) {
  unsigned u = __builtin_bit_cast(unsigned, f);
  u += 0x7fffu + ((u >> 16) & 1u);
  return (unsigned short)(u >> 16);
}

// Emit B in MFMA A-operand fragment order:
//   frag index = ((ct*12 + kb)*64 + lane)*8 + j
//   where n = ct*16 + (lane&15), k = kb*32 + (lane>>4)*8 + j.
// Hot-loop loads then read contiguous 1 KB per (ct,kb).
__global__ __launch_bounds__(384) void build_B(const float* __restrict__ edge,
                                               const float* __restrict__ W,
                                               unsigned short* __restrict__ Bm) {
  const int n = blockIdx.x;   // 0..383  (t*32+o)
  const int k = threadIdx.x;  // 0..383  (s*32+i)
  const int t = n >> 5, o = n & 31;
  const int s = k >> 5, i = k & 31;
  const float* e = edge + (t * S_ + s) * ATTR;
  const float* w = W + (o * IN + i) * ATTR;
  const float v = e[0] * w[0] + e[1] * w[1] + e[2] * w[2];
  const int ct = n >> 4, l15 = n & 15;
  const int kb = k >> 5, quad = (k >> 3) & 3, j = k & 7;
  const int lane = (quad << 4) | l15;
  Bm[((ct * KB_CNT + kb) * 64 + lane) * 8 + j] = f2bf(v);
}

// 4 waves/block, 32 batch rows/wave (2 M-tiles of 16), loop 24 channel tiles.
// MFMA operands: A = B-matrix fragment (channels = M), B = x rows (batch = N).
// C layout gives each lane 4 CONSECUTIVE channels -> one f32x4 store per half.
__global__ __launch_bounds__(256, 3) void fiber_gemm(
    const float* __restrict__ x, const unsigned short* __restrict__ Bm,
    const float* __restrict__ bias, float* __restrict__ out) {
  const int lane = threadIdx.x & 63;
  const int wid  = threadIdx.x >> 6;
  const int col  = lane & 15;   // batch row within 16-tile (MFMA N)
  const int quad = lane >> 4;   // k-subchunk / C channel-group
  const int rowbase = blockIdx.x * 128 + wid * 32;

  // ---- X fragments (MFMA B-operand), whole K in registers (96 VGPRs).
  // Layout: row = col, k = quad*8 + j. Nontemporal: X is streamed exactly once.
  bf16x8 Xf[2][KB_CNT];
#pragma unroll
  for (int mt = 0; mt < 2; ++mt) {
    const float* xp = x + (size_t)(rowbase + mt * 16 + col) * K + quad * 8;
#pragma unroll
    for (int kb = 0; kb < KB_CNT; ++kb) {
      const f32x4 lo = __builtin_nontemporal_load((const f32x4*)(xp + kb * 32));
      const f32x4 hi = __builtin_nontemporal_load((const f32x4*)(xp + kb * 32 + 4));
      short8 sv;
#pragma unroll
      for (int j = 0; j < 4; ++j) {
        sv[j]     = (short)f2bf(lo[j]);
        sv[j + 4] = (short)f2bf(hi[j]);
      }
      Xf[mt][kb] = __builtin_bit_cast(bf16x8, sv);
    }
  }

  // Per-lane bias vectors: channel = ct*16 + quad*4 + r, o = channel & 31.
  f32x4 bv0, bv1;
#pragma unroll
  for (int r = 0; r < 4; ++r) {
    bv0[r] = bias[quad * 4 + r];
    bv1[r] = bias[16 + quad * 4 + r];
  }

#pragma unroll 1
  for (int ct = 0; ct < CT_CNT; ++ct) {
    // Fragment-ordered B: each (ct,kb) is a contiguous 1 KB block; the wave's
    // 64 lanes read lane*16 B -> one fully-coalesced dwordx4 per kb, L1/L2-hot
    // (B is 288 KB total, read near-simultaneously by all 4 waves of a block).
    const unsigned short* bp = Bm + (size_t)ct * CT_SHORTS + lane * 8;
    f32x4 acc0 = {0.f, 0.f, 0.f, 0.f};
    f32x4 acc1 = {0.f, 0.f, 0.f, 0.f};
#pragma unroll
    for (int kb = 0; kb < KB_CNT; ++kb) {
      const bf16x8 Bf = *(const bf16x8*)(bp + kb * FRAG_SHORTS);
      acc0 = __builtin_amdgcn_mfma_f32_16x16x32_bf16(Bf, Xf[0][kb], acc0, 0, 0, 0);
      acc1 = __builtin_amdgcn_mfma_f32_16x16x32_bf16(Bf, Xf[1][kb], acc1, 0, 0, 0);
    }

    // C layout: col = lane&15 = batch row, row = quad*4+r = channel.
    // Lane's 4 acc values are 4 consecutive channels -> one dwordx4 per M-half.
    // Nontemporal: out is written exactly once, never re-read.
    float* op0 = out + (size_t)(rowbase + col) * N + ct * 16 + quad * 4;
    __builtin_nontemporal_store(acc0 + (ct & 1 ? bv1 : bv0), (f32x4*)op0);
    __builtin_nontemporal_store(acc1 + (ct & 1 ? bv1 : bv0), (f32x4*)(op0 + 16 * N));
  }
}

extern "C" void kernel_launch(void* const* d_in, const int* in_sizes, int n_in,
                              void* d_out, int out_size, void* d_ws, size_t ws_size,
                              hipStream_t stream) {
  const float* x    = (const float*)d_in[0];  // [B, S, IN] f32
  const float* edge = (const float*)d_in[1];  // [T, S, ATTR] f32
  const float* W    = (const float*)d_in[2];  // [OUT*IN, ATTR] f32
  const float* bias = (const float*)d_in[3];  // [OUT] f32
  float* out = (float*)d_out;                 // [B, T*OUT] f32
  unsigned short* Bm = (unsigned short*)d_ws; // 384*384 bf16 = 294912 B scratch

  build_B<<<dim3(N), dim3(K), 0, stream>>>(edge, W, Bm);
  fiber_gemm<<<dim3(NB / 128), dim3(256), 0, stream>>>(x, Bm, bias, out);
}